// Round 1
// baseline (1636.558 us; speedup 1.0000x reference)
//
#include <hip/hip_runtime.h>
#include <cstddef>

#define LL 2048
#define TOK 8192   // B*L = 4*2048
#define DM 1024
#define DI 2048
#define NS 16

typedef _Float16 half_t;
typedef __attribute__((ext_vector_type(8))) _Float16 f16x8;
typedef __attribute__((ext_vector_type(4))) _Float16 f16x4;
typedef __attribute__((ext_vector_type(4))) float f32x4;

// ---------- helpers ----------
__device__ __forceinline__ float softplus_f(float x) {
  return fmaxf(x, 0.f) + log1pf(__expf(-fabsf(x)));
}
__device__ __forceinline__ float silu_f(float x) {
  return x / (1.f + __expf(-x));
}
__device__ __forceinline__ void gload_lds16(const void* g, void* l) {
  __builtin_amdgcn_global_load_lds((const __attribute__((address_space(1))) void*)g,
                                   (__attribute__((address_space(3))) void*)l, 16, 0, 0);
}
// DPP row_shr add: after ctrl 0x111,0x112,0x114,0x118 lane15 of each row16 holds the row sum
#define DPP_ADD(v, ctrl) \
  ((v) + __int_as_float(__builtin_amdgcn_update_dpp(0, __float_as_int(v), (ctrl), 0xf, 0xf, true)))

// ---------- static scratch (float units) ----------
//  xh    @ 0            (4,194,304)   x as fp16
//  wlh   @ 4,194,304    (1,048,576)   W_left fp16   } contiguous = [W_left;W_right]
//  wrh   @ 5,242,880    (1,048,576)   W_right fp16  } as one [4096][1024]
//  wdh   @ 6,291,456    (2,097,152)   W_delta hi
//  wdl   @ 8,388,608    (2,097,152)   W_delta lo
//  woh   @ 10,485,760   (1,048,576)
//  left  @ 11,534,336   (16,777,216)
//  xc    @ 28,311,552   (16,777,216)
//  xch   @ 45,088,768   (8,388,608)   xc hi fp16
//  dlt   @ 61,865,984   (16,777,216)
//  gate  @ 78,643,200   (16,777,216)
//  y     @ 95,420,416   (16,777,216)
//  nrmh  @ 112,197,632  (8,388,608)   LN out fp16
//  bc    @ 120,586,240  (262,144)     packed: [row][2n]=B_n, [2n+1]=C_n
//  wbch  @ 120,848,384  (32,768)      [W_B;W_C] as fp16 [32][2048]
__device__ float g_buf[120881152];

// ---------- fp32 -> fp16 staging ----------
__global__ __launch_bounds__(256) void f2h_k(const float* __restrict__ in,
                                             half_t* __restrict__ out, int n4) {
  const int i = blockIdx.x * 256 + threadIdx.x;
  if (i >= n4) return;
  const float4 v = ((const float4*)in)[i];
  f16x4 o;
  o[0] = (half_t)v.x; o[1] = (half_t)v.y; o[2] = (half_t)v.z; o[3] = (half_t)v.w;
  ((f16x4*)out)[i] = o;
}

// ---------- fp32 -> (hi, lo) fp16 split staging ----------
__global__ __launch_bounds__(256) void f2h2_k(const float* __restrict__ in,
                                              half_t* __restrict__ hi,
                                              half_t* __restrict__ lo, int n4) {
  const int i = blockIdx.x * 256 + threadIdx.x;
  if (i >= n4) return;
  const float4 v = ((const float4*)in)[i];
  f16x4 h, l;
  h[0] = (half_t)v.x; h[1] = (half_t)v.y; h[2] = (half_t)v.z; h[3] = (half_t)v.w;
  l[0] = (half_t)(v.x - (float)h[0]);
  l[1] = (half_t)(v.y - (float)h[1]);
  l[2] = (half_t)(v.z - (float)h[2]);
  l[3] = (half_t)(v.w - (float)h[3]);
  ((f16x4*)hi)[i] = h;
  ((f16x4*)lo)[i] = l;
}

// ---------- fp16 MFMA GEMM: C[M,N] = act(A[M,K] @ W[N,K]^T + bias), fp32 out --
template <int ACT>   // 0 none, 1 silu
__global__ __launch_bounds__(256) void gemm_mfma(const half_t* __restrict__ A,
                                                 const half_t* __restrict__ W,
                                                 const float* __restrict__ bias,
                                                 float* __restrict__ C,
                                                 int M, int N, int K) {
  __shared__ half_t lA[4096];   // 8 KB
  __shared__ half_t lB[4096];   // 8 KB
  const int tid = threadIdx.x;
  const int bm0 = blockIdx.y * 128, bn0 = blockIdx.x * 128;
  const int lane = tid & 63, wave = tid >> 6;
  const int q = lane >> 4, mr = lane & 15;
  const int wm = (wave >> 1) * 64, wn = (wave & 1) * 64;
  const int flat0 = tid, flat1 = tid + 256;
  const int kc0 = flat0 >> 7, r0 = flat0 & 127;
  const int kc1 = flat1 >> 7, r1 = flat1 & 127;

  f32x4 acc[4][4];
#pragma unroll
  for (int i = 0; i < 4; ++i)
#pragma unroll
    for (int j = 0; j < 4; ++j) acc[i][j] = (f32x4){0.f, 0.f, 0.f, 0.f};

  for (int k0 = 0; k0 < K; k0 += 32) {
    gload_lds16(A + (size_t)(bm0 + r0) * K + k0 + kc0 * 8, lA + (size_t)flat0 * 8);
    gload_lds16(A + (size_t)(bm0 + r1) * K + k0 + kc1 * 8, lA + (size_t)flat1 * 8);
    gload_lds16(W + (size_t)(bn0 + r0) * K + k0 + kc0 * 8, lB + (size_t)flat0 * 8);
    gload_lds16(W + (size_t)(bn0 + r1) * K + k0 + kc1 * 8, lB + (size_t)flat1 * 8);
    __syncthreads();
    f16x8 af[4], bg[4];
#pragma unroll
    for (int t = 0; t < 4; ++t) {
      af[t] = *(const f16x8*)(lA + ((q << 10) + ((wm + t * 16 + mr) << 3)));
      bg[t] = *(const f16x8*)(lB + ((q << 10) + ((wn + t * 16 + mr) << 3)));
    }
#pragma unroll
    for (int i = 0; i < 4; ++i)
#pragma unroll
      for (int j = 0; j < 4; ++j)
        acc[i][j] = __builtin_amdgcn_mfma_f32_16x16x32_f16(af[i], bg[j], acc[i][j], 0, 0, 0);
    __syncthreads();
  }

#pragma unroll
  for (int i = 0; i < 4; ++i) {
#pragma unroll
    for (int j = 0; j < 4; ++j) {
      const int col = bn0 + wn + j * 16 + mr;
      const float bv = bias ? bias[col] : 0.f;
#pragma unroll
      for (int r = 0; r < 4; ++r) {
        const int row = bm0 + wm + i * 16 + q * 4 + r;
        float v = acc[i][j][r] + bv;
        if (ACT == 1) v = silu_f(v);
        C[(size_t)row * N + col] = v;
      }
    }
  }
}

// ---------- fused left+gate GEMM: W = [W_left;W_right] (4096 x 1024) ----------
// cols < DI -> left (no act); cols >= DI -> gate (silu). Tile is 128-wide and
// DI % 128 == 0, so the branch is block-uniform.
__global__ __launch_bounds__(256) void gemm_mfma_lg(const half_t* __restrict__ A,
                                                    const half_t* __restrict__ W,
                                                    float* __restrict__ left,
                                                    float* __restrict__ gate) {
  __shared__ half_t lA[4096];
  __shared__ half_t lB[4096];
  const int tid = threadIdx.x;
  const int bm0 = blockIdx.y * 128, bn0 = blockIdx.x * 128;
  const int K = DM;
  const int lane = tid & 63, wave = tid >> 6;
  const int q = lane >> 4, mr = lane & 15;
  const int wm = (wave >> 1) * 64, wn = (wave & 1) * 64;
  const int flat1 = tid + 256;
  const int kc0 = tid >> 7, r0 = tid & 127;
  const int kc1 = flat1 >> 7, r1 = flat1 & 127;

  f32x4 acc[4][4];
#pragma unroll
  for (int i = 0; i < 4; ++i)
#pragma unroll
    for (int j = 0; j < 4; ++j) acc[i][j] = (f32x4){0.f, 0.f, 0.f, 0.f};

  for (int k0 = 0; k0 < K; k0 += 32) {
    gload_lds16(A + (size_t)(bm0 + r0) * K + k0 + kc0 * 8, lA + (size_t)tid * 8);
    gload_lds16(A + (size_t)(bm0 + r1) * K + k0 + kc1 * 8, lA + (size_t)flat1 * 8);
    gload_lds16(W + (size_t)(bn0 + r0) * K + k0 + kc0 * 8, lB + (size_t)tid * 8);
    gload_lds16(W + (size_t)(bn0 + r1) * K + k0 + kc1 * 8, lB + (size_t)flat1 * 8);
    __syncthreads();
    f16x8 af[4], bg[4];
#pragma unroll
    for (int t = 0; t < 4; ++t) {
      af[t] = *(const f16x8*)(lA + ((q << 10) + ((wm + t * 16 + mr) << 3)));
      bg[t] = *(const f16x8*)(lB + ((q << 10) + ((wn + t * 16 + mr) << 3)));
    }
#pragma unroll
    for (int i = 0; i < 4; ++i)
#pragma unroll
      for (int j = 0; j < 4; ++j)
        acc[i][j] = __builtin_amdgcn_mfma_f32_16x16x32_f16(af[i], bg[j], acc[i][j], 0, 0, 0);
    __syncthreads();
  }

  const int is_gate = (bn0 >= DI);
  float* out = is_gate ? gate : left;
  const int cb = bn0 - (is_gate ? DI : 0);
#pragma unroll
  for (int i = 0; i < 4; ++i) {
#pragma unroll
    for (int j = 0; j < 4; ++j) {
      const int col = cb + wn + j * 16 + mr;
#pragma unroll
      for (int r = 0; r < 4; ++r) {
        const int row = bm0 + wm + i * 16 + q * 4 + r;
        float v = acc[i][j][r];
        if (is_gate) v = silu_f(v);
        out[(size_t)row * DI + col] = v;
      }
    }
  }
}

// ---------- 2-term split GEMM, 256x256 tile, 512 threads (8 waves) ----------
// acc += Ah*Wh + Ah*Wl.  Double-buffered LDS prefetch pipeline: next K-tile's
// global_load_lds issued BEFORE current tile's ds_read+MFMA, one barrier per
// K-step.  Wave tile 128x64 (2M x 4N wave grid) minimizes LDS-read bytes per
// MFMA (256B; the split doubles B-side traffic so M-heavy waves win).
// LDS 96 KB -> 1 block/CU; grid 8x32 = 256 blocks = exactly 1/CU.
__global__ __launch_bounds__(512, 2) void gemm_mfma_split(const half_t* __restrict__ Ah,
                                                          const half_t* __restrict__ Wh,
                                                          const half_t* __restrict__ Wl,
                                                          const float* __restrict__ bias,
                                                          float* __restrict__ C,
                                                          int M, int N, int K) {
  __shared__ half_t lAh[2][8192];   // [buf][kc4][256][8]  2x16 KB
  __shared__ half_t lBh[2][8192];   // 2x16 KB
  __shared__ half_t lBl[2][8192];   // 2x16 KB
  const int tid = threadIdx.x;
  const int bm0 = blockIdx.y * 256, bn0 = blockIdx.x * 256;
  const int lane = tid & 63, wave = tid >> 6;
  const int q = lane >> 4, mr = lane & 15;
  const int wm = (wave >> 2) * 128, wn = (wave & 3) * 64;
  // staging: 1024 16B-chunks per panel, 2 per thread per panel (6 loads total)
  const int f0 = tid, f1 = tid + 512;
  const int kc0 = f0 >> 8, r0 = f0 & 255;
  const int kc1 = f1 >> 8, r1 = f1 & 255;

#define STAGE_S(bufp, kk)                                                            \
  do {                                                                               \
    gload_lds16(Ah + (size_t)(bm0 + r0) * K + (kk) + kc0 * 8, lAh[bufp] + f0 * 8);   \
    gload_lds16(Ah + (size_t)(bm0 + r1) * K + (kk) + kc1 * 8, lAh[bufp] + f1 * 8);   \
    gload_lds16(Wh + (size_t)(bn0 + r0) * K + (kk) + kc0 * 8, lBh[bufp] + f0 * 8);   \
    gload_lds16(Wh + (size_t)(bn0 + r1) * K + (kk) + kc1 * 8, lBh[bufp] + f1 * 8);   \
    gload_lds16(Wl + (size_t)(bn0 + r0) * K + (kk) + kc0 * 8, lBl[bufp] + f0 * 8);   \
    gload_lds16(Wl + (size_t)(bn0 + r1) * K + (kk) + kc1 * 8, lBl[bufp] + f1 * 8);   \
  } while (0)

  f32x4 acc[8][4];
#pragma unroll
  for (int i = 0; i < 8; ++i)
#pragma unroll
    for (int j = 0; j < 4; ++j) acc[i][j] = (f32x4){0.f, 0.f, 0.f, 0.f};

  // prologue: stage first K-tile into buf 0 (syncthreads drains vmcnt)
  STAGE_S(0, 0);
  __syncthreads();

  int cur = 0;
  for (int k0 = 0; k0 < K; k0 += 32) {
    // prefetch next K-tile into the other buffer (latency hides under MFMA)
    if (k0 + 32 < K) STAGE_S(cur ^ 1, k0 + 32);

    const int qb = q << 11;  // q * 2048 halfs
    const f16x8* pA = (const f16x8*)(lAh[cur] + qb);
    const f16x8* pBh = (const f16x8*)(lBh[cur] + qb);
    const f16x8* pBl = (const f16x8*)(lBl[cur] + qb);
    f16x8 ah[8], bh4[4], bl4[4];
#pragma unroll
    for (int j = 0; j < 4; ++j) {
      bh4[j] = pBh[wn + j * 16 + mr];
      bl4[j] = pBl[wn + j * 16 + mr];
    }
#pragma unroll
    for (int i = 0; i < 8; ++i) ah[i] = pA[wm + i * 16 + mr];

    __builtin_amdgcn_s_setprio(1);
#pragma unroll
    for (int i = 0; i < 8; ++i)
#pragma unroll
      for (int j = 0; j < 4; ++j)
        acc[i][j] = __builtin_amdgcn_mfma_f32_16x16x32_f16(ah[i], bh4[j], acc[i][j], 0, 0, 0);
#pragma unroll
    for (int i = 0; i < 8; ++i)
#pragma unroll
      for (int j = 0; j < 4; ++j)
        acc[i][j] = __builtin_amdgcn_mfma_f32_16x16x32_f16(ah[i], bl4[j], acc[i][j], 0, 0, 0);
    __builtin_amdgcn_s_setprio(0);

    // one barrier per K-step: drains this step's prefetch (issued ~1 MFMA-phase
    // ago) and orders LDS reads of buf[cur] before next step's overwrite
    __syncthreads();
    cur ^= 1;
  }
#undef STAGE_S

#pragma unroll
  for (int i = 0; i < 8; ++i) {
#pragma unroll
    for (int j = 0; j < 4; ++j) {
      const int col = bn0 + wn + j * 16 + mr;
      const float bv = bias[col];
#pragma unroll
      for (int r = 0; r < 4; ++r) {
        const int row = bm0 + wm + i * 16 + q * 4 + r;
        float v = softplus_f(acc[i][j][r] + bv);
        v = fminf(fmaxf(v, 1e-4f), 10.f);
        C[(size_t)row * N + col] = v;
      }
    }
  }
}

// ---------- skinny MFMA GEMM for B/C: bc[M,32] = xch @ [W_B;W_C]^T ----------
__global__ __launch_bounds__(256) void bc_mfma(const half_t* __restrict__ A,
                                               const half_t* __restrict__ Wbc,
                                               float* __restrict__ bc) {
  __shared__ half_t lA[4096];   // [kc4][128][8]  8 KB
  __shared__ half_t lB[1024];   // [kc4][32][8]   2 KB
  const int tid = threadIdx.x;
  const int bm0 = blockIdx.x * 128;
  const int lane = tid & 63, wave = tid >> 6;
  const int q = lane >> 4, mr = lane & 15;
  const int wm = wave * 32;
  const int flat1 = tid + 256;
  const int kcA0 = tid >> 7, rA0 = tid & 127;
  const int kcA1 = flat1 >> 7, rA1 = flat1 & 127;
  const int kcB = tid >> 5, rB = tid & 31;   // threads 0..127

  f32x4 acc[2][2];
#pragma unroll
  for (int i = 0; i < 2; ++i)
#pragma unroll
    for (int j = 0; j < 2; ++j) acc[i][j] = (f32x4){0.f, 0.f, 0.f, 0.f};

  for (int k0 = 0; k0 < DI; k0 += 32) {
    gload_lds16(A + (size_t)(bm0 + rA0) * DI + k0 + kcA0 * 8, lA + (size_t)tid * 8);
    gload_lds16(A + (size_t)(bm0 + rA1) * DI + k0 + kcA1 * 8, lA + (size_t)flat1 * 8);
    if (tid < 128)
      gload_lds16(Wbc + (size_t)rB * DI + k0 + kcB * 8, lB + (size_t)tid * 8);
    __syncthreads();
    f16x8 af[2], bg[2];
#pragma unroll
    for (int t = 0; t < 2; ++t) {
      af[t] = *(const f16x8*)(lA + ((q << 10) + ((wm + t * 16 + mr) << 3)));
      bg[t] = *(const f16x8*)(lB + ((q << 8) + ((t * 16 + mr) << 3)));
    }
#pragma unroll
    for (int i = 0; i < 2; ++i)
#pragma unroll
      for (int j = 0; j < 2; ++j)
        acc[i][j] = __builtin_amdgcn_mfma_f32_16x16x32_f16(af[i], bg[j], acc[i][j], 0, 0, 0);
    __syncthreads();
  }

#pragma unroll
  for (int i = 0; i < 2; ++i) {
#pragma unroll
    for (int j = 0; j < 2; ++j) {
#pragma unroll
      for (int r = 0; r < 4; ++r) {
        const int row = bm0 + wm + i * 16 + q * 4 + r;
        bc[(size_t)row * 32 + 2 * mr + j] = acc[i][j][r];
      }
    }
  }
}

// ---------- causal depthwise conv(4) + bias + silu (fp32 + fp16 out) ----------
__global__ __launch_bounds__(256) void conv_silu_k(const float* __restrict__ left,
                                                   const float* __restrict__ cw,
                                                   const float* __restrict__ cb,
                                                   float* __restrict__ xc,
                                                   half_t* __restrict__ xch) {
  const int idx = blockIdx.x * 256 + threadIdx.x;  // over TOK*DI
  const int d = idx & (DI - 1);
  const int bt = idx >> 11;
  const int t = bt & (LL - 1);
  const float4 wv = *(const float4*)(cw + (size_t)d * 4);
  float acc = cb[d];
  const size_t base = (size_t)idx;
  if (t >= 3) {
    acc += left[base - 3 * DI] * wv.x + left[base - 2 * DI] * wv.y +
           left[base - DI] * wv.z + left[base] * wv.w;
  } else {
    acc += left[base] * wv.w;
    if (t >= 1) acc += left[base - DI] * wv.z;
    if (t >= 2) acc += left[base - 2 * DI] * wv.y;
  }
  const float v = silu_f(acc);
  xc[base] = v;
  xch[base] = (half_t)v;
}

// ---------- selective scan: DPP reduce, packed LDS, prefetch pipeline ----------
#define ST 32
__global__ __launch_bounds__(256) void scan_k(const float* __restrict__ delta,
                                              const float* __restrict__ xc,
                                              const float* __restrict__ gate,
                                              const float* __restrict__ bcp,
                                              const float* __restrict__ A_log,
                                              float* __restrict__ y) {
  __shared__ float dx2[16 * 68];
  __shared__ float bcs[ST * 32];
  __shared__ float ys[ST * 16];
  const int tid = threadIdx.x;
  const int b  = blockIdx.x >> 7;
  const int d0 = (blockIdx.x & 127) << 4;
  const int n  = tid & 15;
  const int ch = tid >> 4;
  const float An = -softplus_f(A_log[n]);

  const int t_a = tid >> 4, c_a = tid & 15;
  const int t_b = t_a + 16;

  float h = 0.f;
  const size_t batch_base = (size_t)b * LL * DI + d0;
  const size_t batch_bc   = (size_t)b * LL * 32;

  size_t rb_cur = batch_base;
  float g0, g1;
  {
    const size_t ra = rb_cur + (size_t)t_a * DI + c_a;
    const size_t rbx = rb_cur + (size_t)t_b * DI + c_a;
    const float d0v = delta[ra], x0v = xc[ra];
    const float d1v = delta[rbx], x1v = xc[rbx];
    g0 = gate[ra]; g1 = gate[rbx];
    const float2 b0 = *(const float2*)&bcp[batch_bc + (size_t)t_a * 32 + 2 * c_a];
    const float2 b1 = *(const float2*)&bcp[batch_bc + (size_t)t_b * 32 + 2 * c_a];
    *(float2*)&dx2[c_a * 68 + t_a * 2] = make_float2(d0v, x0v);
    *(float2*)&dx2[c_a * 68 + t_b * 2] = make_float2(d1v, x1v);
    *(float2*)&bcs[t_a * 32 + 2 * c_a] = b0;
    *(float2*)&bcs[t_b * 32 + 2 * c_a] = b1;
  }
  __syncthreads();

  for (int it = 0; it < LL / ST; ++it) {
    float nd0, nx0, ng0, nd1, nx1, ng1;
    float2 nb0, nb1;
    const size_t rb_nxt = batch_base + (size_t)(it + 1) * ST * DI;
    if (it + 1 < LL / ST) {
      const size_t ra = rb_nxt + (size_t)t_a * DI + c_a;
      const size_t rbx = rb_nxt + (size_t)t_b * DI + c_a;
      nd0 = delta[ra]; nx0 = xc[ra]; ng0 = gate[ra];
      nd1 = delta[rbx]; nx1 = xc[rbx]; ng1 = gate[rbx];
      const size_t bcb = batch_bc + (size_t)(it + 1) * ST * 32;
      nb0 = *(const float2*)&bcp[bcb + (size_t)t_a * 32 + 2 * c_a];
      nb1 = *(const float2*)&bcp[bcb + (size_t)t_b * 32 + 2 * c_a];
    }

    const float* dxp = &dx2[ch * 68];
#pragma unroll
    for (int tt = 0; tt < ST; tt += 2) {
      const float4 v = *(const float4*)&dxp[tt * 2];
      const float2 bc0 = *(const float2*)&bcs[tt * 32 + 2 * n];
      const float2 bc1 = *(const float2*)&bcs[(tt + 1) * 32 + 2 * n];
      float ab = __expf(v.x * An);
      h = fmaf(ab, h, v.x * v.y * bc0.x);
      float p = h * bc0.y;
      p = DPP_ADD(p, 0x111); p = DPP_ADD(p, 0x112);
      p = DPP_ADD(p, 0x114); p = DPP_ADD(p, 0x118);
      if (n == 15) ys[tt * 16 + ch] = p;
      ab = __expf(v.z * An);
      h = fmaf(ab, h, v.z * v.w * bc1.x);
      p = h * bc1.y;
      p = DPP_ADD(p, 0x111); p = DPP_ADD(p, 0x112);
      p = DPP_ADD(p, 0x114); p = DPP_ADD(p, 0x118);
      if (n == 15) ys[(tt + 1) * 16 + ch] = p;
    }
    __syncthreads();

    if (it + 1 < LL / ST) {
      *(float2*)&dx2[c_a * 68 + t_a * 2] = make_float2(nd0, nx0);
      *(float2*)&dx2[c_a * 68 + t_b * 2] = make_float2(nd1, nx1);
      *(float2*)&bcs[t_a * 32 + 2 * c_a] = nb0;
      *(float2*)&bcs[t_b * 32 + 2 * c_a] = nb1;
    }
    y[rb_cur + (size_t)t_a * DI + c_a] = ys[t_a * 16 + c_a] * g0;
    y[rb_cur + (size_t)t_b * DI + c_a] = ys[t_b * 16 + c_a] * g1;
    g0 = ng0; g1 = ng1;
    rb_cur = rb_nxt;
    __syncthreads();
  }
}

// ---------- layernorm over d_inner (fp16 out for MFMA consumer) ----------
__global__ __launch_bounds__(256) void ln_k(const float* __restrict__ y,
                                            const float* __restrict__ gam,
                                            const float* __restrict__ bet,
                                            half_t* __restrict__ outn) {
  const int row = blockIdx.x;
  const int tid = threadIdx.x;
  const float* yr = y + (size_t)row * DI;
  const float4 v0 = ((const float4*)yr)[tid];
  const float4 v1 = ((const float4*)yr)[tid + 256];
  float s = v0.x + v0.y + v0.z + v0.w + v1.x + v1.y + v1.z + v1.w;
  float q = v0.x * v0.x + v0.y * v0.y + v0.z * v0.z + v0.w * v0.w +
            v1.x * v1.x + v1.y * v1.y + v1.z * v1.z + v1.w * v1.w;
  for (int off = 32; off > 0; off >>= 1) {
    s += __shfl_down(s, off);
    q += __shfl_down(q, off);
  }
  __shared__ float sred[4], qred[4];
  const int wid = tid >> 6;
  if ((tid & 63) == 0) { sred[wid] = s; qred[wid] = q; }
  __syncthreads();
  s = sred[0] + sred[1] + sred[2] + sred[3];
  q = qred[0] + qred[1] + qred[2] + qred[3];
  const float mu = s * (1.f / DI);
  const float rs = rsqrtf(q * (1.f / DI) - mu * mu + 1e-5f);
  half_t* orow = outn + (size_t)row * DI;
  const int c0 = tid * 4, c1 = (tid + 256) * 4;
  f16x4 o;
  o[0] = (half_t)((v0.x - mu) * rs * gam[c0 + 0] + bet[c0 + 0]);
  o[1] = (half_t)((v0.y - mu) * rs * gam[c0 + 1] + bet[c0 + 1]);
  o[2] = (half_t)((v0.z - mu) * rs * gam[c0 + 2] + bet[c0 + 2]);
  o[3] = (half_t)((v0.w - mu) * rs * gam[c0 + 3] + bet[c0 + 3]);
  ((f16x4*)orow)[tid] = o;
  o[0] = (half_t)((v1.x - mu) * rs * gam[c1 + 0] + bet[c1 + 0]);
  o[1] = (half_t)((v1.y - mu) * rs * gam[c1 + 1] + bet[c1 + 1]);
  o[2] = (half_t)((v1.z - mu) * rs * gam[c1 + 2] + bet[c1 + 2]);
  o[3] = (half_t)((v1.w - mu) * rs * gam[c1 + 3] + bet[c1 + 3]);
  ((f16x4*)orow)[tid + 256] = o;
}

// ---------- host launch ----------
extern "C" void kernel_launch(void* const* d_in, const int* in_sizes, int n_in,
                              void* d_out, int out_size, void* d_ws, size_t ws_size,
                              hipStream_t stream) {
  const float* x       = (const float*)d_in[0];
  const float* W_left  = (const float*)d_in[1];
  const float* conv_w  = (const float*)d_in[2];
  const float* conv_b  = (const float*)d_in[3];
  const float* W_delta = (const float*)d_in[4];
  const float* b_delta = (const float*)d_in[5];
  const float* W_B     = (const float*)d_in[6];
  const float* W_C     = (const float*)d_in[7];
  const float* A_log   = (const float*)d_in[8];
  const float* W_right = (const float*)d_in[9];
  const float* ln_g    = (const float*)d_in[10];
  const float* ln_b    = (const float*)d_in[11];
  const float* W_out   = (const float*)d_in[12];

  float* buf = nullptr;
  hipGetSymbolAddress((void**)&buf, HIP_SYMBOL(g_buf));
  half_t* xh   = (half_t*)(buf + 0);
  half_t* wlgh = (half_t*)(buf + 4194304);   // [W_left;W_right] 4096x1024 fp16
  half_t* wrh  = (half_t*)(buf + 5242880);
  half_t* wdh  = (half_t*)(buf + 6291456);
  half_t* wdl  = (half_t*)(buf + 8388608);
  half_t* woh  = (half_t*)(buf + 10485760);
  float* left  = buf + 11534336;
  float* xc    = buf + 28311552;
  half_t* xch  = (half_t*)(buf + 45088768);
  float* dlt   = buf + 61865984;
  float* gate  = buf + 78643200;
  float* yv    = buf + 95420416;
  half_t* nrmh = (half_t*)(buf + 112197632);
  float* bc    = buf + 120586240;
  half_t* wbch = (half_t*)(buf + 120848384);

  // fp32 -> fp16 staging
  f2h_k<<<8192, 256, 0, stream>>>(x, xh, TOK * DM / 4);
  f2h_k<<<2048, 256, 0, stream>>>(W_left, wlgh, DI * DM / 4);
  f2h_k<<<2048, 256, 0, stream>>>(W_right, wrh, DI * DM / 4);
  f2h_k<<<2048, 256, 0, stream>>>(W_out, woh, DM * DI / 4);
  f2h2_k<<<4096, 256, 0, stream>>>(W_delta, wdh, wdl, DI * DI / 4);
  f2h_k<<<32, 256, 0, stream>>>(W_B, wbch, NS * DI / 4);
  f2h_k<<<32, 256, 0, stream>>>(W_C, wbch + NS * DI, NS * DI / 4);

  // left = x @ W_left^T ; gate = silu(x @ W_right^T)  -- fused, N=4096
  gemm_mfma_lg<<<dim3(2 * DI / 128, TOK / 128), 256, 0, stream>>>(xh, wlgh, left, gate);
  // xc = silu(causal_conv(left))  (fp32 + fp16)
  conv_silu_k<<<TOK * DI / 256, 256, 0, stream>>>(left, conv_w, conv_b, xc, xch);
  // delta = clip(softplus(xc @ W_delta^T + b_delta))  [256x256 tile, dbuf prefetch]
  gemm_mfma_split<<<dim3(DI / 256, TOK / 256), 512, 0, stream>>>(xch, wdh, wdl, b_delta, dlt, TOK, DI, DI);
  // B/C projections via MFMA (interleaved output)
  bc_mfma<<<TOK / 128, 256, 0, stream>>>(xch, wbch, bc);
  // selective scan with fused gate (DPP reduce + prefetch pipeline)
  scan_k<<<512, 256, 0, stream>>>(dlt, xc, gate, bc, A_log, yv);
  // layernorm -> fp16
  ln_k<<<TOK, 256, 0, stream>>>(yv, ln_g, ln_b, nrmh);
  // out = nrm @ W_out^T  (fp32 store to d_out)
  gemm_mfma<0><<<dim3(DM / 128, TOK / 128), 256, 0, stream>>>(nrmh, woh, nullptr, (float*)d_out, TOK, DM, DI);
}

// Round 2
// 928.893 us; speedup vs baseline: 1.7618x; 1.7618x over previous
//
#include <hip/hip_runtime.h>
#include <cstddef>

#define LL 2048
#define TOK 8192   // B*L = 4*2048
#define DM 1024
#define DI 2048
#define NS 16

typedef _Float16 half_t;
typedef __attribute__((ext_vector_type(8))) _Float16 f16x8;
typedef __attribute__((ext_vector_type(4))) _Float16 f16x4;
typedef __attribute__((ext_vector_type(4))) float f32x4;

// ---------- helpers ----------
__device__ __forceinline__ float softplus_f(float x) {
  return fmaxf(x, 0.f) + log1pf(__expf(-fabsf(x)));
}
__device__ __forceinline__ float silu_f(float x) {
  return x / (1.f + __expf(-x));
}
__device__ __forceinline__ void gload_lds16(const void* g, void* l) {
  __builtin_amdgcn_global_load_lds((const __attribute__((address_space(1))) void*)g,
                                   (__attribute__((address_space(3))) void*)l, 16, 0, 0);
}
// DPP row_shr add: after ctrl 0x111,0x112,0x114,0x118 lane15 of each row16 holds the row sum
#define DPP_ADD(v, ctrl) \
  ((v) + __int_as_float(__builtin_amdgcn_update_dpp(0, __float_as_int(v), (ctrl), 0xf, 0xf, true)))

// ---------- static scratch (float units) ----------
//  xh    @ 0            (4,194,304)   x as fp16
//  wlh   @ 4,194,304    (1,048,576)   W_left fp16   } contiguous = [W_left;W_right]
//  wrh   @ 5,242,880    (1,048,576)   W_right fp16  } as one [4096][1024]
//  wdh   @ 6,291,456    (2,097,152)   W_delta hi
//  wdl   @ 8,388,608    (2,097,152)   W_delta lo
//  woh   @ 10,485,760   (1,048,576)
//  left  @ 11,534,336   (16,777,216)
//  xc    @ 28,311,552   (16,777,216)
//  xch   @ 45,088,768   (8,388,608)   xc hi fp16
//  dlt   @ 61,865,984   (16,777,216)
//  gate  @ 78,643,200   (16,777,216)
//  y     @ 95,420,416   (16,777,216)
//  nrmh  @ 112,197,632  (8,388,608)   LN out fp16
//  bc    @ 120,586,240  (262,144)     packed: [row][2n]=B_n, [2n+1]=C_n
//  wbch  @ 120,848,384  (32,768)      [W_B;W_C] as fp16 [32][2048]
__device__ float g_buf[120881152];

// ---------- fp32 -> fp16 staging ----------
__global__ __launch_bounds__(256) void f2h_k(const float* __restrict__ in,
                                             half_t* __restrict__ out, int n4) {
  const int i = blockIdx.x * 256 + threadIdx.x;
  if (i >= n4) return;
  const float4 v = ((const float4*)in)[i];
  f16x4 o;
  o[0] = (half_t)v.x; o[1] = (half_t)v.y; o[2] = (half_t)v.z; o[3] = (half_t)v.w;
  ((f16x4*)out)[i] = o;
}

// ---------- fp32 -> (hi, lo) fp16 split staging ----------
__global__ __launch_bounds__(256) void f2h2_k(const float* __restrict__ in,
                                              half_t* __restrict__ hi,
                                              half_t* __restrict__ lo, int n4) {
  const int i = blockIdx.x * 256 + threadIdx.x;
  if (i >= n4) return;
  const float4 v = ((const float4*)in)[i];
  f16x4 h, l;
  h[0] = (half_t)v.x; h[1] = (half_t)v.y; h[2] = (half_t)v.z; h[3] = (half_t)v.w;
  l[0] = (half_t)(v.x - (float)h[0]);
  l[1] = (half_t)(v.y - (float)h[1]);
  l[2] = (half_t)(v.z - (float)h[2]);
  l[3] = (half_t)(v.w - (float)h[3]);
  ((f16x4*)hi)[i] = h;
  ((f16x4*)lo)[i] = l;
}

// ---------- fp16 MFMA GEMM: C[M,N] = act(A[M,K] @ W[N,K]^T + bias), fp32 out --
template <int ACT>   // 0 none, 1 silu
__global__ __launch_bounds__(256) void gemm_mfma(const half_t* __restrict__ A,
                                                 const half_t* __restrict__ W,
                                                 const float* __restrict__ bias,
                                                 float* __restrict__ C,
                                                 int M, int N, int K) {
  __shared__ half_t lA[4096];   // 8 KB
  __shared__ half_t lB[4096];   // 8 KB
  const int tid = threadIdx.x;
  const int bm0 = blockIdx.y * 128, bn0 = blockIdx.x * 128;
  const int lane = tid & 63, wave = tid >> 6;
  const int q = lane >> 4, mr = lane & 15;
  const int wm = (wave >> 1) * 64, wn = (wave & 1) * 64;
  const int flat0 = tid, flat1 = tid + 256;
  const int kc0 = flat0 >> 7, r0 = flat0 & 127;
  const int kc1 = flat1 >> 7, r1 = flat1 & 127;

  f32x4 acc[4][4];
#pragma unroll
  for (int i = 0; i < 4; ++i)
#pragma unroll
    for (int j = 0; j < 4; ++j) acc[i][j] = (f32x4){0.f, 0.f, 0.f, 0.f};

  for (int k0 = 0; k0 < K; k0 += 32) {
    gload_lds16(A + (size_t)(bm0 + r0) * K + k0 + kc0 * 8, lA + (size_t)flat0 * 8);
    gload_lds16(A + (size_t)(bm0 + r1) * K + k0 + kc1 * 8, lA + (size_t)flat1 * 8);
    gload_lds16(W + (size_t)(bn0 + r0) * K + k0 + kc0 * 8, lB + (size_t)flat0 * 8);
    gload_lds16(W + (size_t)(bn0 + r1) * K + k0 + kc1 * 8, lB + (size_t)flat1 * 8);
    __syncthreads();
    f16x8 af[4], bg[4];
#pragma unroll
    for (int t = 0; t < 4; ++t) {
      af[t] = *(const f16x8*)(lA + ((q << 10) + ((wm + t * 16 + mr) << 3)));
      bg[t] = *(const f16x8*)(lB + ((q << 10) + ((wn + t * 16 + mr) << 3)));
    }
#pragma unroll
    for (int i = 0; i < 4; ++i)
#pragma unroll
      for (int j = 0; j < 4; ++j)
        acc[i][j] = __builtin_amdgcn_mfma_f32_16x16x32_f16(af[i], bg[j], acc[i][j], 0, 0, 0);
    __syncthreads();
  }

#pragma unroll
  for (int i = 0; i < 4; ++i) {
#pragma unroll
    for (int j = 0; j < 4; ++j) {
      const int col = bn0 + wn + j * 16 + mr;
      const float bv = bias ? bias[col] : 0.f;
#pragma unroll
      for (int r = 0; r < 4; ++r) {
        const int row = bm0 + wm + i * 16 + q * 4 + r;
        float v = acc[i][j][r] + bv;
        if (ACT == 1) v = silu_f(v);
        C[(size_t)row * N + col] = v;
      }
    }
  }
}

// ---------- fused left+gate GEMM: W = [W_left;W_right] (4096 x 1024) ----------
// cols < DI -> left (no act); cols >= DI -> gate (silu). Tile is 128-wide and
// DI % 128 == 0, so the branch is block-uniform.
__global__ __launch_bounds__(256) void gemm_mfma_lg(const half_t* __restrict__ A,
                                                    const half_t* __restrict__ W,
                                                    float* __restrict__ left,
                                                    float* __restrict__ gate) {
  __shared__ half_t lA[4096];
  __shared__ half_t lB[4096];
  const int tid = threadIdx.x;
  const int bm0 = blockIdx.y * 128, bn0 = blockIdx.x * 128;
  const int K = DM;
  const int lane = tid & 63, wave = tid >> 6;
  const int q = lane >> 4, mr = lane & 15;
  const int wm = (wave >> 1) * 64, wn = (wave & 1) * 64;
  const int flat1 = tid + 256;
  const int kc0 = tid >> 7, r0 = tid & 127;
  const int kc1 = flat1 >> 7, r1 = flat1 & 127;

  f32x4 acc[4][4];
#pragma unroll
  for (int i = 0; i < 4; ++i)
#pragma unroll
    for (int j = 0; j < 4; ++j) acc[i][j] = (f32x4){0.f, 0.f, 0.f, 0.f};

  for (int k0 = 0; k0 < K; k0 += 32) {
    gload_lds16(A + (size_t)(bm0 + r0) * K + k0 + kc0 * 8, lA + (size_t)tid * 8);
    gload_lds16(A + (size_t)(bm0 + r1) * K + k0 + kc1 * 8, lA + (size_t)flat1 * 8);
    gload_lds16(W + (size_t)(bn0 + r0) * K + k0 + kc0 * 8, lB + (size_t)tid * 8);
    gload_lds16(W + (size_t)(bn0 + r1) * K + k0 + kc1 * 8, lB + (size_t)flat1 * 8);
    __syncthreads();
    f16x8 af[4], bg[4];
#pragma unroll
    for (int t = 0; t < 4; ++t) {
      af[t] = *(const f16x8*)(lA + ((q << 10) + ((wm + t * 16 + mr) << 3)));
      bg[t] = *(const f16x8*)(lB + ((q << 10) + ((wn + t * 16 + mr) << 3)));
    }
#pragma unroll
    for (int i = 0; i < 4; ++i)
#pragma unroll
      for (int j = 0; j < 4; ++j)
        acc[i][j] = __builtin_amdgcn_mfma_f32_16x16x32_f16(af[i], bg[j], acc[i][j], 0, 0, 0);
    __syncthreads();
  }

  const int is_gate = (bn0 >= DI);
  float* out = is_gate ? gate : left;
  const int cb = bn0 - (is_gate ? DI : 0);
#pragma unroll
  for (int i = 0; i < 4; ++i) {
#pragma unroll
    for (int j = 0; j < 4; ++j) {
      const int col = cb + wn + j * 16 + mr;
#pragma unroll
      for (int r = 0; r < 4; ++r) {
        const int row = bm0 + wm + i * 16 + q * 4 + r;
        float v = acc[i][j][r];
        if (is_gate) v = silu_f(v);
        out[(size_t)row * DI + col] = v;
      }
    }
  }
}

// ---------- 2-term split GEMM, 256x128 tile, 512 threads (8 waves) ----------
// acc += Ah*Wh + Ah*Wl.  Round-0 geometry (acc[4][4] = 64 regs -> 60 VGPR, no
// spill) + double-buffered LDS prefetch: next K-tile's global_load_lds issued
// BEFORE current tile's ds_read+MFMA, ONE barrier per K-step.  The barrier's
// vmcnt(0) drain now lands a full 32-MFMA phase after issue instead of
// immediately, and 2 blocks/CU (64 KB LDS) overlap residual stalls.
__global__ __launch_bounds__(512, 4) void gemm_mfma_split(const half_t* __restrict__ Ah,
                                                          const half_t* __restrict__ Wh,
                                                          const half_t* __restrict__ Wl,
                                                          const float* __restrict__ bias,
                                                          float* __restrict__ C,
                                                          int M, int N, int K) {
  __shared__ half_t lAh[2][8192];   // [buf][kc4][256][8]  2x16 KB
  __shared__ half_t lBh[2][4096];   // [buf][kc4][128][8]  2x8 KB
  __shared__ half_t lBl[2][4096];   // 2x8 KB
  const int tid = threadIdx.x;
  const int bm0 = blockIdx.y * 256, bn0 = blockIdx.x * 128;
  const int lane = tid & 63, wave = tid >> 6;
  const int q = lane >> 4, mr = lane & 15;
  const int wm = (wave >> 1) * 64, wn = (wave & 1) * 64;
  // A staging: 1024 chunks, 2 per thread
  const int aflat1 = tid + 512;
  const int akc0 = tid >> 8, ar0 = tid & 255;
  const int akc1 = aflat1 >> 8, ar1 = aflat1 & 255;
  // W staging: 512 chunks, 1 per thread (both Wh and Wl)
  const int wkc = tid >> 7, wr = tid & 127;

#define STAGE_S(bufp, kk)                                                                  \
  do {                                                                                     \
    gload_lds16(Ah + (size_t)(bm0 + ar0) * K + (kk) + akc0 * 8, lAh[bufp] + tid * 8);      \
    gload_lds16(Ah + (size_t)(bm0 + ar1) * K + (kk) + akc1 * 8, lAh[bufp] + aflat1 * 8);   \
    gload_lds16(Wh + (size_t)(bn0 + wr) * K + (kk) + wkc * 8, lBh[bufp] + tid * 8);        \
    gload_lds16(Wl + (size_t)(bn0 + wr) * K + (kk) + wkc * 8, lBl[bufp] + tid * 8);        \
  } while (0)

  f32x4 acc[4][4];
#pragma unroll
  for (int i = 0; i < 4; ++i)
#pragma unroll
    for (int j = 0; j < 4; ++j) acc[i][j] = (f32x4){0.f, 0.f, 0.f, 0.f};

  // prologue: stage first K-tile into buf 0 (__syncthreads drains vmcnt)
  STAGE_S(0, 0);
  __syncthreads();

  int cur = 0;
  for (int k0 = 0; k0 < K; k0 += 32) {
    // prefetch next K-tile into the other buffer; latency hides under MFMA
    if (k0 + 32 < K) STAGE_S(cur ^ 1, k0 + 32);

    f16x8 ah[4], bh4[4], bl4[4];
#pragma unroll
    for (int t = 0; t < 4; ++t) {
      const int ao = (q << 11) + ((wm + t * 16 + mr) << 3);   // q*256*8
      const int bo = (q << 10) + ((wn + t * 16 + mr) << 3);   // q*128*8
      ah[t] = *(const f16x8*)(lAh[cur] + ao);
      bh4[t] = *(const f16x8*)(lBh[cur] + bo);
      bl4[t] = *(const f16x8*)(lBl[cur] + bo);
    }

    __builtin_amdgcn_s_setprio(1);
#pragma unroll
    for (int i = 0; i < 4; ++i)
#pragma unroll
      for (int j = 0; j < 4; ++j)
        acc[i][j] = __builtin_amdgcn_mfma_f32_16x16x32_f16(ah[i], bh4[j], acc[i][j], 0, 0, 0);
#pragma unroll
    for (int i = 0; i < 4; ++i)
#pragma unroll
      for (int j = 0; j < 4; ++j)
        acc[i][j] = __builtin_amdgcn_mfma_f32_16x16x32_f16(ah[i], bl4[j], acc[i][j], 0, 0, 0);
    __builtin_amdgcn_s_setprio(0);

    // one barrier per K-step: drains this step's prefetch (issued one
    // MFMA-phase ago) and orders buf[cur] reads before next overwrite
    __syncthreads();
    cur ^= 1;
  }
#undef STAGE_S

#pragma unroll
  for (int i = 0; i < 4; ++i) {
#pragma unroll
    for (int j = 0; j < 4; ++j) {
      const int col = bn0 + wn + j * 16 + mr;
      const float bv = bias[col];
#pragma unroll
      for (int r = 0; r < 4; ++r) {
        const int row = bm0 + wm + i * 16 + q * 4 + r;
        float v = softplus_f(acc[i][j][r] + bv);
        v = fminf(fmaxf(v, 1e-4f), 10.f);
        C[(size_t)row * N + col] = v;
      }
    }
  }
}

// ---------- skinny MFMA GEMM for B/C: bc[M,32] = xch @ [W_B;W_C]^T ----------
__global__ __launch_bounds__(256) void bc_mfma(const half_t* __restrict__ A,
                                               const half_t* __restrict__ Wbc,
                                               float* __restrict__ bc) {
  __shared__ half_t lA[4096];   // [kc4][128][8]  8 KB
  __shared__ half_t lB[1024];   // [kc4][32][8]   2 KB
  const int tid = threadIdx.x;
  const int bm0 = blockIdx.x * 128;
  const int lane = tid & 63, wave = tid >> 6;
  const int q = lane >> 4, mr = lane & 15;
  const int wm = wave * 32;
  const int flat1 = tid + 256;
  const int kcA0 = tid >> 7, rA0 = tid & 127;
  const int kcA1 = flat1 >> 7, rA1 = flat1 & 127;
  const int kcB = tid >> 5, rB = tid & 31;   // threads 0..127

  f32x4 acc[2][2];
#pragma unroll
  for (int i = 0; i < 2; ++i)
#pragma unroll
    for (int j = 0; j < 2; ++j) acc[i][j] = (f32x4){0.f, 0.f, 0.f, 0.f};

  for (int k0 = 0; k0 < DI; k0 += 32) {
    gload_lds16(A + (size_t)(bm0 + rA0) * DI + k0 + kcA0 * 8, lA + (size_t)tid * 8);
    gload_lds16(A + (size_t)(bm0 + rA1) * DI + k0 + kcA1 * 8, lA + (size_t)flat1 * 8);
    if (tid < 128)
      gload_lds16(Wbc + (size_t)rB * DI + k0 + kcB * 8, lB + (size_t)tid * 8);
    __syncthreads();
    f16x8 af[2], bg[2];
#pragma unroll
    for (int t = 0; t < 2; ++t) {
      af[t] = *(const f16x8*)(lA + ((q << 10) + ((wm + t * 16 + mr) << 3)));
      bg[t] = *(const f16x8*)(lB + ((q << 8) + ((t * 16 + mr) << 3)));
    }
#pragma unroll
    for (int i = 0; i < 2; ++i)
#pragma unroll
      for (int j = 0; j < 2; ++j)
        acc[i][j] = __builtin_amdgcn_mfma_f32_16x16x32_f16(af[i], bg[j], acc[i][j], 0, 0, 0);
    __syncthreads();
  }

#pragma unroll
  for (int i = 0; i < 2; ++i) {
#pragma unroll
    for (int j = 0; j < 2; ++j) {
#pragma unroll
      for (int r = 0; r < 4; ++r) {
        const int row = bm0 + wm + i * 16 + q * 4 + r;
        bc[(size_t)row * 32 + 2 * mr + j] = acc[i][j][r];
      }
    }
  }
}

// ---------- causal depthwise conv(4) + bias + silu (fp32 + fp16 out) ----------
__global__ __launch_bounds__(256) void conv_silu_k(const float* __restrict__ left,
                                                   const float* __restrict__ cw,
                                                   const float* __restrict__ cb,
                                                   float* __restrict__ xc,
                                                   half_t* __restrict__ xch) {
  const int idx = blockIdx.x * 256 + threadIdx.x;  // over TOK*DI
  const int d = idx & (DI - 1);
  const int bt = idx >> 11;
  const int t = bt & (LL - 1);
  const float4 wv = *(const float4*)(cw + (size_t)d * 4);
  float acc = cb[d];
  const size_t base = (size_t)idx;
  if (t >= 3) {
    acc += left[base - 3 * DI] * wv.x + left[base - 2 * DI] * wv.y +
           left[base - DI] * wv.z + left[base] * wv.w;
  } else {
    acc += left[base] * wv.w;
    if (t >= 1) acc += left[base - DI] * wv.z;
    if (t >= 2) acc += left[base - 2 * DI] * wv.y;
  }
  const float v = silu_f(acc);
  xc[base] = v;
  xch[base] = (half_t)v;
}

// ---------- selective scan: DPP reduce, packed LDS, prefetch pipeline ----------
#define ST 32
__global__ __launch_bounds__(256) void scan_k(const float* __restrict__ delta,
                                              const float* __restrict__ xc,
                                              const float* __restrict__ gate,
                                              const float* __restrict__ bcp,
                                              const float* __restrict__ A_log,
                                              float* __restrict__ y) {
  __shared__ float dx2[16 * 68];
  __shared__ float bcs[ST * 32];
  __shared__ float ys[ST * 16];
  const int tid = threadIdx.x;
  const int b  = blockIdx.x >> 7;
  const int d0 = (blockIdx.x & 127) << 4;
  const int n  = tid & 15;
  const int ch = tid >> 4;
  const float An = -softplus_f(A_log[n]);

  const int t_a = tid >> 4, c_a = tid & 15;
  const int t_b = t_a + 16;

  float h = 0.f;
  const size_t batch_base = (size_t)b * LL * DI + d0;
  const size_t batch_bc   = (size_t)b * LL * 32;

  size_t rb_cur = batch_base;
  float g0, g1;
  {
    const size_t ra = rb_cur + (size_t)t_a * DI + c_a;
    const size_t rbx = rb_cur + (size_t)t_b * DI + c_a;
    const float d0v = delta[ra], x0v = xc[ra];
    const float d1v = delta[rbx], x1v = xc[rbx];
    g0 = gate[ra]; g1 = gate[rbx];
    const float2 b0 = *(const float2*)&bcp[batch_bc + (size_t)t_a * 32 + 2 * c_a];
    const float2 b1 = *(const float2*)&bcp[batch_bc + (size_t)t_b * 32 + 2 * c_a];
    *(float2*)&dx2[c_a * 68 + t_a * 2] = make_float2(d0v, x0v);
    *(float2*)&dx2[c_a * 68 + t_b * 2] = make_float2(d1v, x1v);
    *(float2*)&bcs[t_a * 32 + 2 * c_a] = b0;
    *(float2*)&bcs[t_b * 32 + 2 * c_a] = b1;
  }
  __syncthreads();

  for (int it = 0; it < LL / ST; ++it) {
    float nd0, nx0, ng0, nd1, nx1, ng1;
    float2 nb0, nb1;
    const size_t rb_nxt = batch_base + (size_t)(it + 1) * ST * DI;
    if (it + 1 < LL / ST) {
      const size_t ra = rb_nxt + (size_t)t_a * DI + c_a;
      const size_t rbx = rb_nxt + (size_t)t_b * DI + c_a;
      nd0 = delta[ra]; nx0 = xc[ra]; ng0 = gate[ra];
      nd1 = delta[rbx]; nx1 = xc[rbx]; ng1 = gate[rbx];
      const size_t bcb = batch_bc + (size_t)(it + 1) * ST * 32;
      nb0 = *(const float2*)&bcp[bcb + (size_t)t_a * 32 + 2 * c_a];
      nb1 = *(const float2*)&bcp[bcb + (size_t)t_b * 32 + 2 * c_a];
    }

    const float* dxp = &dx2[ch * 68];
#pragma unroll
    for (int tt = 0; tt < ST; tt += 2) {
      const float4 v = *(const float4*)&dxp[tt * 2];
      const float2 bc0 = *(const float2*)&bcs[tt * 32 + 2 * n];
      const float2 bc1 = *(const float2*)&bcs[(tt + 1) * 32 + 2 * n];
      float ab = __expf(v.x * An);
      h = fmaf(ab, h, v.x * v.y * bc0.x);
      float p = h * bc0.y;
      p = DPP_ADD(p, 0x111); p = DPP_ADD(p, 0x112);
      p = DPP_ADD(p, 0x114); p = DPP_ADD(p, 0x118);
      if (n == 15) ys[tt * 16 + ch] = p;
      ab = __expf(v.z * An);
      h = fmaf(ab, h, v.z * v.w * bc1.x);
      p = h * bc1.y;
      p = DPP_ADD(p, 0x111); p = DPP_ADD(p, 0x112);
      p = DPP_ADD(p, 0x114); p = DPP_ADD(p, 0x118);
      if (n == 15) ys[(tt + 1) * 16 + ch] = p;
    }
    __syncthreads();

    if (it + 1 < LL / ST) {
      *(float2*)&dx2[c_a * 68 + t_a * 2] = make_float2(nd0, nx0);
      *(float2*)&dx2[c_a * 68 + t_b * 2] = make_float2(nd1, nx1);
      *(float2*)&bcs[t_a * 32 + 2 * c_a] = nb0;
      *(float2*)&bcs[t_b * 32 + 2 * c_a] = nb1;
    }
    y[rb_cur + (size_t)t_a * DI + c_a] = ys[t_a * 16 + c_a] * g0;
    y[rb_cur + (size_t)t_b * DI + c_a] = ys[t_b * 16 + c_a] * g1;
    g0 = ng0; g1 = ng1;
    rb_cur = rb_nxt;
    __syncthreads();
  }
}

// ---------- layernorm over d_inner (fp16 out for MFMA consumer) ----------
__global__ __launch_bounds__(256) void ln_k(const float* __restrict__ y,
                                            const float* __restrict__ gam,
                                            const float* __restrict__ bet,
                                            half_t* __restrict__ outn) {
  const int row = blockIdx.x;
  const int tid = threadIdx.x;
  const float* yr = y + (size_t)row * DI;
  const float4 v0 = ((const float4*)yr)[tid];
  const float4 v1 = ((const float4*)yr)[tid + 256];
  float s = v0.x + v0.y + v0.z + v0.w + v1.x + v1.y + v1.z + v1.w;
  float q = v0.x * v0.x + v0.y * v0.y + v0.z * v0.z + v0.w * v0.w +
            v1.x * v1.x + v1.y * v1.y + v1.z * v1.z + v1.w * v1.w;
  for (int off = 32; off > 0; off >>= 1) {
    s += __shfl_down(s, off);
    q += __shfl_down(q, off);
  }
  __shared__ float sred[4], qred[4];
  const int wid = tid >> 6;
  if ((tid & 63) == 0) { sred[wid] = s; qred[wid] = q; }
  __syncthreads();
  s = sred[0] + sred[1] + sred[2] + sred[3];
  q = qred[0] + qred[1] + qred[2] + qred[3];
  const float mu = s * (1.f / DI);
  const float rs = rsqrtf(q * (1.f / DI) - mu * mu + 1e-5f);
  half_t* orow = outn + (size_t)row * DI;
  const int c0 = tid * 4, c1 = (tid + 256) * 4;
  f16x4 o;
  o[0] = (half_t)((v0.x - mu) * rs * gam[c0 + 0] + bet[c0 + 0]);
  o[1] = (half_t)((v0.y - mu) * rs * gam[c0 + 1] + bet[c0 + 1]);
  o[2] = (half_t)((v0.z - mu) * rs * gam[c0 + 2] + bet[c0 + 2]);
  o[3] = (half_t)((v0.w - mu) * rs * gam[c0 + 3] + bet[c0 + 3]);
  ((f16x4*)orow)[tid] = o;
  o[0] = (half_t)((v1.x - mu) * rs * gam[c1 + 0] + bet[c1 + 0]);
  o[1] = (half_t)((v1.y - mu) * rs * gam[c1 + 1] + bet[c1 + 1]);
  o[2] = (half_t)((v1.z - mu) * rs * gam[c1 + 2] + bet[c1 + 2]);
  o[3] = (half_t)((v1.w - mu) * rs * gam[c1 + 3] + bet[c1 + 3]);
  ((f16x4*)orow)[tid + 256] = o;
}

// ---------- host launch ----------
extern "C" void kernel_launch(void* const* d_in, const int* in_sizes, int n_in,
                              void* d_out, int out_size, void* d_ws, size_t ws_size,
                              hipStream_t stream) {
  const float* x       = (const float*)d_in[0];
  const float* W_left  = (const float*)d_in[1];
  const float* conv_w  = (const float*)d_in[2];
  const float* conv_b  = (const float*)d_in[3];
  const float* W_delta = (const float*)d_in[4];
  const float* b_delta = (const float*)d_in[5];
  const float* W_B     = (const float*)d_in[6];
  const float* W_C     = (const float*)d_in[7];
  const float* A_log   = (const float*)d_in[8];
  const float* W_right = (const float*)d_in[9];
  const float* ln_g    = (const float*)d_in[10];
  const float* ln_b    = (const float*)d_in[11];
  const float* W_out   = (const float*)d_in[12];

  float* buf = nullptr;
  hipGetSymbolAddress((void**)&buf, HIP_SYMBOL(g_buf));
  half_t* xh   = (half_t*)(buf + 0);
  half_t* wlgh = (half_t*)(buf + 4194304);   // [W_left;W_right] 4096x1024 fp16
  half_t* wrh  = (half_t*)(buf + 5242880);
  half_t* wdh  = (half_t*)(buf + 6291456);
  half_t* wdl  = (half_t*)(buf + 8388608);
  half_t* woh  = (half_t*)(buf + 10485760);
  float* left  = buf + 11534336;
  float* xc    = buf + 28311552;
  half_t* xch  = (half_t*)(buf + 45088768);
  float* dlt   = buf + 61865984;
  float* gate  = buf + 78643200;
  float* yv    = buf + 95420416;
  half_t* nrmh = (half_t*)(buf + 112197632);
  float* bc    = buf + 120586240;
  half_t* wbch = (half_t*)(buf + 120848384);

  // fp32 -> fp16 staging
  f2h_k<<<8192, 256, 0, stream>>>(x, xh, TOK * DM / 4);
  f2h_k<<<2048, 256, 0, stream>>>(W_left, wlgh, DI * DM / 4);
  f2h_k<<<2048, 256, 0, stream>>>(W_right, wrh, DI * DM / 4);
  f2h_k<<<2048, 256, 0, stream>>>(W_out, woh, DM * DI / 4);
  f2h2_k<<<4096, 256, 0, stream>>>(W_delta, wdh, wdl, DI * DI / 4);
  f2h_k<<<32, 256, 0, stream>>>(W_B, wbch, NS * DI / 4);
  f2h_k<<<32, 256, 0, stream>>>(W_C, wbch + NS * DI, NS * DI / 4);

  // left = x @ W_left^T ; gate = silu(x @ W_right^T)  -- fused, N=4096
  gemm_mfma_lg<<<dim3(2 * DI / 128, TOK / 128), 256, 0, stream>>>(xh, wlgh, left, gate);
  // xc = silu(causal_conv(left))  (fp32 + fp16)
  conv_silu_k<<<TOK * DI / 256, 256, 0, stream>>>(left, conv_w, conv_b, xc, xch);
  // delta = clip(softplus(xc @ W_delta^T + b_delta))  [256x128 tile, dbuf prefetch]
  gemm_mfma_split<<<dim3(DI / 128, TOK / 256), 512, 0, stream>>>(xch, wdh, wdl, b_delta, dlt, TOK, DI, DI);
  // B/C projections via MFMA (interleaved output)
  bc_mfma<<<TOK / 128, 256, 0, stream>>>(xch, wbch, bc);
  // selective scan with fused gate (DPP reduce + prefetch pipeline)
  scan_k<<<512, 256, 0, stream>>>(dlt, xc, gate, bc, A_log, yv);
  // layernorm -> fp16
  ln_k<<<TOK, 256, 0, stream>>>(yv, ln_g, ln_b, nrmh);
  // out = nrm @ W_out^T  (fp32 store to d_out)
  gemm_mfma<0><<<dim3(DM / 128, TOK / 128), 256, 0, stream>>>(nrmh, woh, nullptr, (float*)d_out, TOK, DM, DI);
}